// Round 1
// baseline (673.352 us; speedup 1.0000x reference)
//
#include <hip/hip_runtime.h>
#include <cstddef>

#define HIDDEN 128
#define BN_EPS 1e-5f

// ---------- K1: zero degree counters + BN accumulators ----------
__global__ void k_zero(int* __restrict__ cnt, float* __restrict__ bn, int N) {
    int i = blockIdx.x * 256 + threadIdx.x;
    if (i < N) cnt[i] = 0;
    if (blockIdx.x == 0 && threadIdx.x < 256) bn[threadIdx.x] = 0.f;
}

// ---------- K2: in-degree histogram over target nodes ----------
__global__ void k_count(const int* __restrict__ col, int* __restrict__ cnt, int E) {
    int e = blockIdx.x * 256 + threadIdx.x;
    if (e < E) atomicAdd(&cnt[col[e]], 1);
}

// ---------- K3: single-block exclusive scan -> CSR offsets, dinv, reset cnt ----------
__global__ __launch_bounds__(1024) void k_scan(int* __restrict__ cnt, int* __restrict__ off,
                                               float* __restrict__ dinv, int N) {
    __shared__ int s[1024];
    int tid = threadIdx.x;
    int chunk = (N + 1023) / 1024;
    int start = tid * chunk;
    int end = min(start + chunk, N);
    int local = 0;
    for (int j = start; j < end; ++j) local += cnt[j];
    s[tid] = local;
    __syncthreads();
    for (int o = 1; o < 1024; o <<= 1) {  // Hillis-Steele inclusive scan
        int v = (tid >= o) ? s[tid - o] : 0;
        __syncthreads();
        s[tid] += v;
        __syncthreads();
    }
    int run = s[tid] - local;  // exclusive prefix for this chunk
    for (int j = start; j < end; ++j) {
        int c = cnt[j];
        off[j] = run;
        run += c;
        // deg includes self-loop: in-degree + 1  (deg >= 1 always)
        dinv[j] = rsqrtf((float)(c + 1));
        cnt[j] = 0;  // reset: reused as placement cursor in K5
    }
    if (tid == 1023) off[N] = s[1023];
}

// ---------- K4: xw = x @ W (fp32, LDS tiled, XOR-swizzled x-tile) ----------
// Block: 256 threads, 128 rows. LDS: W 64KB + x-tile 64KB = 128KB (1 block/CU).
// Thread (rg,cg) computes rows rg*8..+7, cols {4cg..4cg+3, 64+4cg..+3} (8x8 acc).
__global__ __launch_bounds__(256) void k_gemm(const float* __restrict__ x,
                                              const float* __restrict__ W,
                                              float* __restrict__ xw, int N) {
    __shared__ float4 ws4[HIDDEN * 32];  // [k][chunk c4], plain row-major
    __shared__ float4 xt4[HIDDEN * 32];  // [r][swizzled chunk]
    int tid = threadIdx.x;
    int row0 = blockIdx.x * 128;

    // stage W: coalesced float4, conflict-free writes
    for (int t = tid; t < HIDDEN * 32; t += 256)
        ws4[t] = ((const float4*)W)[t];

    // stage x tile: lanes cover one row's 32 chunks -> coalesced 512B reads;
    // XOR swizzle so main-loop reads (lanes differ in rg) hit distinct bank quads
    for (int t = tid; t < 128 * 32; t += 256) {
        int r = t >> 5;
        int c4 = t & 31;
        int grow = row0 + r;
        float4 v = make_float4(0.f, 0.f, 0.f, 0.f);
        if (grow < N) v = ((const float4*)x)[grow * 32 + c4];
        xt4[r * 32 + (c4 ^ (r & 31) ^ ((r >> 3) & 3))] = v;
    }
    __syncthreads();

    int rg = tid >> 4;  // 0..15 row group
    int cg = tid & 15;  // 0..15 col group
    float acc[8][8];
#pragma unroll
    for (int i = 0; i < 8; ++i)
#pragma unroll
        for (int j = 0; j < 8; ++j) acc[i][j] = 0.f;

#pragma unroll 2
    for (int k4 = 0; k4 < 32; ++k4) {
        float4 xv[8];
#pragma unroll
        for (int i = 0; i < 8; ++i) {
            int r = rg * 8 + i;
            xv[i] = xt4[r * 32 + (k4 ^ (r & 31) ^ ((r >> 3) & 3))];
        }
#pragma unroll
        for (int kk = 0; kk < 4; ++kk) {
            int k = k4 * 4 + kk;
            float4 w0 = ws4[k * 32 + cg];        // cols 4cg..4cg+3   (2-way -> free)
            float4 w1 = ws4[k * 32 + 16 + cg];   // cols 64+4cg..+3
#pragma unroll
            for (int i = 0; i < 8; ++i) {
                float xs = ((const float*)&xv[i])[kk];
                acc[i][0] = fmaf(xs, w0.x, acc[i][0]);
                acc[i][1] = fmaf(xs, w0.y, acc[i][1]);
                acc[i][2] = fmaf(xs, w0.z, acc[i][2]);
                acc[i][3] = fmaf(xs, w0.w, acc[i][3]);
                acc[i][4] = fmaf(xs, w1.x, acc[i][4]);
                acc[i][5] = fmaf(xs, w1.y, acc[i][5]);
                acc[i][6] = fmaf(xs, w1.z, acc[i][6]);
                acc[i][7] = fmaf(xs, w1.w, acc[i][7]);
            }
        }
    }

#pragma unroll
    for (int i = 0; i < 8; ++i) {
        int grow = row0 + rg * 8 + i;
        if (grow < N) {
            ((float4*)xw)[grow * 32 + cg]      = make_float4(acc[i][0], acc[i][1], acc[i][2], acc[i][3]);
            ((float4*)xw)[grow * 32 + 16 + cg] = make_float4(acc[i][4], acc[i][5], acc[i][6], acc[i][7]);
        }
    }
}

// ---------- K5: counting-sort edges by target -> CSR source list ----------
__global__ void k_place(const int* __restrict__ row, const int* __restrict__ col,
                        const int* __restrict__ off, int* __restrict__ cur,
                        int* __restrict__ srcs, int E) {
    int e = blockIdx.x * 256 + threadIdx.x;
    if (e < E) {
        int c = col[e];
        int p = atomicAdd(&cur[c], 1);
        srcs[off[c] + p] = row[e];
    }
}

// ---------- K6: per-node gather-aggregate (one wave per node, no f32 atomics) ----------
// agg[i] = dinv_i * (sum_{r->i} dinv_r * xw[r]) + dinv_i^2 * xw[i] + b
__global__ __launch_bounds__(256) void k_gather(const float* __restrict__ xw,
                                                const float* __restrict__ dinv,
                                                const int* __restrict__ off,
                                                const int* __restrict__ srcs,
                                                const float* __restrict__ b,
                                                float* __restrict__ out, int N) {
    int lane = threadIdx.x & 63;
    int w = (blockIdx.x * 256 + threadIdx.x) >> 6;
    int nw = (gridDim.x * 256) >> 6;
    float2 bb = ((const float2*)b)[lane];
    for (int i = w; i < N; i += nw) {
        float di = dinv[i];
        float2 acc = ((const float2*)xw)[i * 64 + lane];  // self-loop term
        acc.x *= di;
        acc.y *= di;
        int e0 = off[i], e1 = off[i + 1];
        for (int j = e0; j < e1; ++j) {
            int r = srcs[j];
            float dr = dinv[r];
            float2 v = ((const float2*)xw)[r * 64 + lane];
            acc.x = fmaf(dr, v.x, acc.x);
            acc.y = fmaf(dr, v.y, acc.y);
        }
        float2 o;
        o.x = fmaf(acc.x, di, bb.x);
        o.y = fmaf(acc.y, di, bb.y);
        ((float2*)out)[i * 64 + lane] = o;
    }
}

// ---------- K7: BN column stats (sum, sumsq) ----------
__global__ __launch_bounds__(256) void k_stats(const float* __restrict__ agg,
                                               float* __restrict__ bn, int N) {
    __shared__ float ssum[HIDDEN];
    __shared__ float ssq[HIDDEN];
    int tid = threadIdx.x;
    int lane = tid & 63;
    int w = (blockIdx.x * 256 + tid) >> 6;
    int nw = (gridDim.x * 256) >> 6;
    float2 s = make_float2(0.f, 0.f), q = make_float2(0.f, 0.f);
    for (int i = w; i < N; i += nw) {
        float2 v = ((const float2*)agg)[i * 64 + lane];
        s.x += v.x;
        s.y += v.y;
        q.x = fmaf(v.x, v.x, q.x);
        q.y = fmaf(v.y, v.y, q.y);
    }
    if (tid < HIDDEN) { ssum[tid] = 0.f; ssq[tid] = 0.f; }
    __syncthreads();
    atomicAdd(&ssum[2 * lane],     s.x);
    atomicAdd(&ssum[2 * lane + 1], s.y);
    atomicAdd(&ssq[2 * lane],      q.x);
    atomicAdd(&ssq[2 * lane + 1],  q.y);
    __syncthreads();
    if (tid < HIDDEN) {
        atomicAdd(&bn[tid],          ssum[tid]);
        atomicAdd(&bn[HIDDEN + tid], ssq[tid]);
    }
}

// ---------- K8: BN normalize (biased var) + gamma/beta + ReLU, in place ----------
__global__ __launch_bounds__(256) void k_apply(float* __restrict__ out,
                                               const float* __restrict__ bn,
                                               const float* __restrict__ gamma,
                                               const float* __restrict__ beta,
                                               int total4, float invN) {
    __shared__ float sc[HIDDEN], sh[HIDDEN];
    int tid = threadIdx.x;
    if (tid < HIDDEN) {
        float mean = bn[tid] * invN;
        float var = bn[HIDDEN + tid] * invN - mean * mean;
        float inv = rsqrtf(var + BN_EPS);
        float g = gamma[tid] * inv;
        sc[tid] = g;
        sh[tid] = beta[tid] - mean * g;
    }
    __syncthreads();
    int idx = blockIdx.x * 256 + tid;
    if (idx < total4) {
        float4 v = ((float4*)out)[idx];
        int c = (idx & 31) * 4;  // 32 float4 chunks per 128-col row
        v.x = fmaxf(fmaf(v.x, sc[c],     sh[c]),     0.f);
        v.y = fmaxf(fmaf(v.y, sc[c + 1], sh[c + 1]), 0.f);
        v.z = fmaxf(fmaf(v.z, sc[c + 2], sh[c + 2]), 0.f);
        v.w = fmaxf(fmaf(v.w, sc[c + 3], sh[c + 3]), 0.f);
        ((float4*)out)[idx] = v;
    }
}

extern "C" void kernel_launch(void* const* d_in, const int* in_sizes, int n_in,
                              void* d_out, int out_size, void* d_ws, size_t ws_size,
                              hipStream_t stream) {
    const float* x     = (const float*)d_in[0];
    const int*   edges = (const int*)d_in[1];   // [2, E] int32 (JAX x64-off)
    const float* W     = (const float*)d_in[2];
    const float* b     = (const float*)d_in[3];
    const float* gamma = (const float*)d_in[4];
    const float* beta  = (const float*)d_in[5];
    float* out = (float*)d_out;

    int N = in_sizes[0] / HIDDEN;
    int E = in_sizes[1] / 2;
    const int* row = edges;      // sources
    const int* col = edges + E;  // targets

    // workspace carve (~56 MB): xw | dinv | cnt | off | srcs | bn
    char* p = (char*)d_ws;
    float* xw   = (float*)p; p += (size_t)N * HIDDEN * sizeof(float);
    float* dinv = (float*)p; p += (size_t)N * sizeof(float);
    int*   cnt  = (int*)p;   p += (size_t)N * sizeof(int);
    int*   off  = (int*)p;   p += ((size_t)N + 4) * sizeof(int);
    int*   srcs = (int*)p;   p += (size_t)E * sizeof(int);
    float* bn   = (float*)p; p += 256 * sizeof(float);

    dim3 blk(256);
    k_zero <<<dim3((N + 255) / 256), blk, 0, stream>>>(cnt, bn, N);
    k_count<<<dim3((E + 255) / 256), blk, 0, stream>>>(col, cnt, E);
    k_scan <<<dim3(1), dim3(1024), 0, stream>>>(cnt, off, dinv, N);
    k_gemm <<<dim3((N + 127) / 128), blk, 0, stream>>>(x, W, xw, N);
    k_place<<<dim3((E + 255) / 256), blk, 0, stream>>>(row, col, off, cnt, srcs, E);
    k_gather<<<dim3(4096), blk, 0, stream>>>(xw, dinv, off, srcs, b, out, N);
    k_stats<<<dim3(512), blk, 0, stream>>>(out, bn, N);
    int total4 = N * (HIDDEN / 4);
    k_apply<<<dim3((total4 + 255) / 256), blk, 0, stream>>>(out, bn, gamma, beta, total4,
                                                            1.0f / (float)N);
}

// Round 2
// 407.028 us; speedup vs baseline: 1.6543x; 1.6543x over previous
//
#include <hip/hip_runtime.h>
#include <cstddef>

#define HIDDEN 128
#define BN_EPS 1e-5f
#define SCAN_CHUNK 1024  // cnt elements per scan block

// ---------- K1: zero degree counters + BN accumulators ----------
__global__ void k_zero(int* __restrict__ cnt, float* __restrict__ bn, int N) {
    int i = blockIdx.x * 256 + threadIdx.x;
    if (i < N) cnt[i] = 0;
    if (blockIdx.x == 0 && threadIdx.x < 256) bn[threadIdx.x] = 0.f;
}

// ---------- K2: in-degree histogram over target nodes ----------
__global__ void k_count(const int* __restrict__ col, int* __restrict__ cnt, int E) {
    int e = blockIdx.x * 256 + threadIdx.x;
    if (e < E) atomicAdd(&cnt[col[e]], 1);
}

// ---------- K3a: per-block partial sums of cnt (1024 elems / block) ----------
__global__ __launch_bounds__(256) void k_partial(const int* __restrict__ cnt,
                                                 int* __restrict__ partials, int N) {
    __shared__ int s[256];
    int tid = threadIdx.x;
    int base = blockIdx.x * SCAN_CHUNK;
    int acc = 0;
#pragma unroll
    for (int k = 0; k < 4; ++k) {
        int idx = base + tid * 4 + k;
        if (idx < N) acc += cnt[idx];
    }
    s[tid] = acc;
    __syncthreads();
    for (int o = 128; o > 0; o >>= 1) {
        if (tid < o) s[tid] += s[tid + o];
        __syncthreads();
    }
    if (tid == 0) partials[blockIdx.x] = s[0];
}

// ---------- K3b: single-block exclusive scan of partials (all in LDS) ----------
__global__ __launch_bounds__(1024) void k_scan_partials(int* __restrict__ partials,
                                                        int* __restrict__ off,
                                                        int NB, int N) {
    __shared__ int s[1024];
    int tid = threadIdx.x;
    int v = (tid < NB) ? partials[tid] : 0;
    s[tid] = v;
    __syncthreads();
    for (int o = 1; o < 1024; o <<= 1) {  // Hillis-Steele inclusive
        int t = (tid >= o) ? s[tid - o] : 0;
        __syncthreads();
        s[tid] += t;
        __syncthreads();
    }
    if (tid < NB) partials[tid] = s[tid] - v;  // exclusive
    if (tid == NB - 1) off[N] = s[tid];        // grand total = E
}

// ---------- K3c: block-local scan + base -> off, dinv, cnt reset ----------
__global__ __launch_bounds__(256) void k_finalize(int* __restrict__ cnt,
                                                  const int* __restrict__ partials,
                                                  int* __restrict__ off,
                                                  float* __restrict__ dinv, int N) {
    __shared__ int s[256];
    int tid = threadIdx.x;
    int base = blockIdx.x * SCAN_CHUNK;
    int c[4];
    int t = 0;
#pragma unroll
    for (int k = 0; k < 4; ++k) {
        int idx = base + tid * 4 + k;
        c[k] = (idx < N) ? cnt[idx] : 0;
        t += c[k];
    }
    s[tid] = t;
    __syncthreads();
    for (int o = 1; o < 256; o <<= 1) {  // Hillis-Steele inclusive over thread totals
        int v = (tid >= o) ? s[tid - o] : 0;
        __syncthreads();
        s[tid] += v;
        __syncthreads();
    }
    int run = partials[blockIdx.x] + s[tid] - t;  // exclusive prefix for this thread
#pragma unroll
    for (int k = 0; k < 4; ++k) {
        int idx = base + tid * 4 + k;
        if (idx < N) {
            off[idx] = run;
            run += c[k];
            dinv[idx] = rsqrtf((float)(c[k] + 1));  // deg includes self-loop
            cnt[idx] = 0;                           // reused as cursor in k_place
        }
    }
}

// ---------- K4: xw = x @ W (fp32, LDS tiled, XOR-swizzled x-tile) ----------
// Block: 256 threads, 128 rows. LDS: W 64KB + x-tile 64KB = 128KB (1 block/CU).
// Thread (rg,cg) computes rows rg*8..+7, cols {4cg..4cg+3, 64+4cg..+3} (8x8 acc).
__global__ __launch_bounds__(256) void k_gemm(const float* __restrict__ x,
                                              const float* __restrict__ W,
                                              float* __restrict__ xw, int N) {
    __shared__ float4 ws4[HIDDEN * 32];  // [k][chunk c4], plain row-major
    __shared__ float4 xt4[HIDDEN * 32];  // [r][swizzled chunk]
    int tid = threadIdx.x;
    int row0 = blockIdx.x * 128;

    for (int t = tid; t < HIDDEN * 32; t += 256)
        ws4[t] = ((const float4*)W)[t];

    for (int t = tid; t < 128 * 32; t += 256) {
        int r = t >> 5;
        int c4 = t & 31;
        int grow = row0 + r;
        float4 v = make_float4(0.f, 0.f, 0.f, 0.f);
        if (grow < N) v = ((const float4*)x)[grow * 32 + c4];
        xt4[r * 32 + (c4 ^ (r & 31) ^ ((r >> 3) & 3))] = v;
    }
    __syncthreads();

    int rg = tid >> 4;
    int cg = tid & 15;
    float acc[8][8];
#pragma unroll
    for (int i = 0; i < 8; ++i)
#pragma unroll
        for (int j = 0; j < 8; ++j) acc[i][j] = 0.f;

#pragma unroll 2
    for (int k4 = 0; k4 < 32; ++k4) {
        float4 xv[8];
#pragma unroll
        for (int i = 0; i < 8; ++i) {
            int r = rg * 8 + i;
            xv[i] = xt4[r * 32 + (k4 ^ (r & 31) ^ ((r >> 3) & 3))];
        }
#pragma unroll
        for (int kk = 0; kk < 4; ++kk) {
            int k = k4 * 4 + kk;
            float4 w0 = ws4[k * 32 + cg];
            float4 w1 = ws4[k * 32 + 16 + cg];
#pragma unroll
            for (int i = 0; i < 8; ++i) {
                float xs = ((const float*)&xv[i])[kk];
                acc[i][0] = fmaf(xs, w0.x, acc[i][0]);
                acc[i][1] = fmaf(xs, w0.y, acc[i][1]);
                acc[i][2] = fmaf(xs, w0.z, acc[i][2]);
                acc[i][3] = fmaf(xs, w0.w, acc[i][3]);
                acc[i][4] = fmaf(xs, w1.x, acc[i][4]);
                acc[i][5] = fmaf(xs, w1.y, acc[i][5]);
                acc[i][6] = fmaf(xs, w1.z, acc[i][6]);
                acc[i][7] = fmaf(xs, w1.w, acc[i][7]);
            }
        }
    }

#pragma unroll
    for (int i = 0; i < 8; ++i) {
        int grow = row0 + rg * 8 + i;
        if (grow < N) {
            ((float4*)xw)[grow * 32 + cg]      = make_float4(acc[i][0], acc[i][1], acc[i][2], acc[i][3]);
            ((float4*)xw)[grow * 32 + 16 + cg] = make_float4(acc[i][4], acc[i][5], acc[i][6], acc[i][7]);
        }
    }
}

// ---------- K5: counting-sort edges by target -> CSR source list ----------
__global__ void k_place(const int* __restrict__ row, const int* __restrict__ col,
                        const int* __restrict__ off, int* __restrict__ cur,
                        int* __restrict__ srcs, int E) {
    int e = blockIdx.x * 256 + threadIdx.x;
    if (e < E) {
        int c = col[e];
        int p = atomicAdd(&cur[c], 1);
        srcs[off[c] + p] = row[e];
    }
}

// ---------- K6: per-node gather-aggregate (one wave per node, no f32 atomics) ----------
// agg[i] = dinv_i * (sum_{r->i} dinv_r * xw[r]) + dinv_i^2 * xw[i] + b
__global__ __launch_bounds__(256) void k_gather(const float* __restrict__ xw,
                                                const float* __restrict__ dinv,
                                                const int* __restrict__ off,
                                                const int* __restrict__ srcs,
                                                const float* __restrict__ b,
                                                float* __restrict__ out, int N) {
    int lane = threadIdx.x & 63;
    int w = (blockIdx.x * 256 + threadIdx.x) >> 6;
    int nw = (gridDim.x * 256) >> 6;
    float2 bb = ((const float2*)b)[lane];
    for (int i = w; i < N; i += nw) {
        float di = dinv[i];
        float2 acc = ((const float2*)xw)[i * 64 + lane];  // self-loop term
        acc.x *= di;
        acc.y *= di;
        int e0 = off[i], e1 = off[i + 1];
        for (int j = e0; j < e1; ++j) {
            int r = srcs[j];
            float dr = dinv[r];
            float2 v = ((const float2*)xw)[r * 64 + lane];
            acc.x = fmaf(dr, v.x, acc.x);
            acc.y = fmaf(dr, v.y, acc.y);
        }
        float2 o;
        o.x = fmaf(acc.x, di, bb.x);
        o.y = fmaf(acc.y, di, bb.y);
        ((float2*)out)[i * 64 + lane] = o;
    }
}

// ---------- K7: BN column stats (sum, sumsq) ----------
__global__ __launch_bounds__(256) void k_stats(const float* __restrict__ agg,
                                               float* __restrict__ bn, int N) {
    __shared__ float ssum[HIDDEN];
    __shared__ float ssq[HIDDEN];
    int tid = threadIdx.x;
    int lane = tid & 63;
    int w = (blockIdx.x * 256 + tid) >> 6;
    int nw = (gridDim.x * 256) >> 6;
    float2 s = make_float2(0.f, 0.f), q = make_float2(0.f, 0.f);
    for (int i = w; i < N; i += nw) {
        float2 v = ((const float2*)agg)[i * 64 + lane];
        s.x += v.x;
        s.y += v.y;
        q.x = fmaf(v.x, v.x, q.x);
        q.y = fmaf(v.y, v.y, q.y);
    }
    if (tid < HIDDEN) { ssum[tid] = 0.f; ssq[tid] = 0.f; }
    __syncthreads();
    atomicAdd(&ssum[2 * lane],     s.x);
    atomicAdd(&ssum[2 * lane + 1], s.y);
    atomicAdd(&ssq[2 * lane],      q.x);
    atomicAdd(&ssq[2 * lane + 1],  q.y);
    __syncthreads();
    if (tid < HIDDEN) {
        atomicAdd(&bn[tid],          ssum[tid]);
        atomicAdd(&bn[HIDDEN + tid], ssq[tid]);
    }
}

// ---------- K8: BN normalize (biased var) + gamma/beta + ReLU, in place ----------
__global__ __launch_bounds__(256) void k_apply(float* __restrict__ out,
                                               const float* __restrict__ bn,
                                               const float* __restrict__ gamma,
                                               const float* __restrict__ beta,
                                               int total4, float invN) {
    __shared__ float sc[HIDDEN], sh[HIDDEN];
    int tid = threadIdx.x;
    if (tid < HIDDEN) {
        float mean = bn[tid] * invN;
        float var = bn[HIDDEN + tid] * invN - mean * mean;
        float inv = rsqrtf(var + BN_EPS);
        float g = gamma[tid] * inv;
        sc[tid] = g;
        sh[tid] = beta[tid] - mean * g;
    }
    __syncthreads();
    int idx = blockIdx.x * 256 + tid;
    if (idx < total4) {
        float4 v = ((float4*)out)[idx];
        int c = (idx & 31) * 4;
        v.x = fmaxf(fmaf(v.x, sc[c],     sh[c]),     0.f);
        v.y = fmaxf(fmaf(v.y, sc[c + 1], sh[c + 1]), 0.f);
        v.z = fmaxf(fmaf(v.z, sc[c + 2], sh[c + 2]), 0.f);
        v.w = fmaxf(fmaf(v.w, sc[c + 3], sh[c + 3]), 0.f);
        ((float4*)out)[idx] = v;
    }
}

extern "C" void kernel_launch(void* const* d_in, const int* in_sizes, int n_in,
                              void* d_out, int out_size, void* d_ws, size_t ws_size,
                              hipStream_t stream) {
    const float* x     = (const float*)d_in[0];
    const int*   edges = (const int*)d_in[1];   // [2, E] int32 (JAX x64-off)
    const float* W     = (const float*)d_in[2];
    const float* b     = (const float*)d_in[3];
    const float* gamma = (const float*)d_in[4];
    const float* beta  = (const float*)d_in[5];
    float* out = (float*)d_out;

    int N = in_sizes[0] / HIDDEN;
    int E = in_sizes[1] / 2;
    const int* row = edges;      // sources
    const int* col = edges + E;  // targets

    int NB = (N + SCAN_CHUNK - 1) / SCAN_CHUNK;  // scan blocks (98 for N=100k)

    // workspace carve (~56 MB): xw | dinv | cnt | off | srcs | bn | partials
    char* p = (char*)d_ws;
    float* xw       = (float*)p; p += (size_t)N * HIDDEN * sizeof(float);
    float* dinv     = (float*)p; p += (size_t)N * sizeof(float);
    int*   cnt      = (int*)p;   p += (size_t)N * sizeof(int);
    int*   off      = (int*)p;   p += ((size_t)N + 4) * sizeof(int);
    int*   srcs     = (int*)p;   p += (size_t)E * sizeof(int);
    float* bn       = (float*)p; p += 256 * sizeof(float);
    int*   partials = (int*)p;   p += (size_t)NB * sizeof(int);

    dim3 blk(256);
    k_zero <<<dim3((N + 255) / 256), blk, 0, stream>>>(cnt, bn, N);
    k_count<<<dim3((E + 255) / 256), blk, 0, stream>>>(col, cnt, E);
    k_partial<<<dim3(NB), blk, 0, stream>>>(cnt, partials, N);
    k_scan_partials<<<dim3(1), dim3(1024), 0, stream>>>(partials, off, NB, N);
    k_finalize<<<dim3(NB), blk, 0, stream>>>(cnt, partials, off, dinv, N);
    k_gemm <<<dim3((N + 127) / 128), blk, 0, stream>>>(x, W, xw, N);
    k_place<<<dim3((E + 255) / 256), blk, 0, stream>>>(row, col, off, cnt, srcs, E);
    k_gather<<<dim3(4096), blk, 0, stream>>>(xw, dinv, off, srcs, b, out, N);
    k_stats<<<dim3(512), blk, 0, stream>>>(out, bn, N);
    int total4 = N * (HIDDEN / 4);
    k_apply<<<dim3((total4 + 255) / 256), blk, 0, stream>>>(out, bn, gamma, beta, total4,
                                                            1.0f / (float)N);
}

// Round 3
// 392.844 us; speedup vs baseline: 1.7140x; 1.0361x over previous
//
#include <hip/hip_runtime.h>
#include <cstddef>

#define HIDDEN 128
#define BN_EPS 1e-5f
#define SCAN_CHUNK 1024  // cnt elements per scan block
#define KC 32            // GEMM k-chunk

// ---------- K1: zero degree counters + BN accumulators ----------
__global__ void k_zero(int* __restrict__ cnt, float* __restrict__ bn, int N) {
    int i = blockIdx.x * 256 + threadIdx.x;
    if (i < N) cnt[i] = 0;
    if (blockIdx.x == 0 && threadIdx.x < 256) bn[threadIdx.x] = 0.f;
}

// ---------- K2: in-degree histogram over target nodes ----------
__global__ void k_count(const int* __restrict__ col, int* __restrict__ cnt, int E) {
    int e = blockIdx.x * 256 + threadIdx.x;
    if (e < E) atomicAdd(&cnt[col[e]], 1);
}

// ---------- K3a: per-block partial sums of cnt (1024 elems / block) ----------
__global__ __launch_bounds__(256) void k_partial(const int* __restrict__ cnt,
                                                 int* __restrict__ partials, int N) {
    __shared__ int s[256];
    int tid = threadIdx.x;
    int base = blockIdx.x * SCAN_CHUNK;
    int acc = 0;
#pragma unroll
    for (int k = 0; k < 4; ++k) {
        int idx = base + tid * 4 + k;
        if (idx < N) acc += cnt[idx];
    }
    s[tid] = acc;
    __syncthreads();
    for (int o = 128; o > 0; o >>= 1) {
        if (tid < o) s[tid] += s[tid + o];
        __syncthreads();
    }
    if (tid == 0) partials[blockIdx.x] = s[0];
}

// ---------- K3b: single-block exclusive scan of partials (all in LDS) ----------
__global__ __launch_bounds__(1024) void k_scan_partials(int* __restrict__ partials,
                                                        int* __restrict__ off,
                                                        int NB, int N) {
    __shared__ int s[1024];
    int tid = threadIdx.x;
    int v = (tid < NB) ? partials[tid] : 0;
    s[tid] = v;
    __syncthreads();
    for (int o = 1; o < 1024; o <<= 1) {
        int t = (tid >= o) ? s[tid - o] : 0;
        __syncthreads();
        s[tid] += t;
        __syncthreads();
    }
    if (tid < NB) partials[tid] = s[tid] - v;
    if (tid == NB - 1) off[N] = s[tid];
}

// ---------- K3c: block-local scan + base -> off, dinv, cnt reset ----------
__global__ __launch_bounds__(256) void k_finalize(int* __restrict__ cnt,
                                                  const int* __restrict__ partials,
                                                  int* __restrict__ off,
                                                  float* __restrict__ dinv, int N) {
    __shared__ int s[256];
    int tid = threadIdx.x;
    int base = blockIdx.x * SCAN_CHUNK;
    int c[4];
    int t = 0;
#pragma unroll
    for (int k = 0; k < 4; ++k) {
        int idx = base + tid * 4 + k;
        c[k] = (idx < N) ? cnt[idx] : 0;
        t += c[k];
    }
    s[tid] = t;
    __syncthreads();
    for (int o = 1; o < 256; o <<= 1) {
        int v = (tid >= o) ? s[tid - o] : 0;
        __syncthreads();
        s[tid] += v;
        __syncthreads();
    }
    int run = partials[blockIdx.x] + s[tid] - t;
#pragma unroll
    for (int k = 0; k < 4; ++k) {
        int idx = base + tid * 4 + k;
        if (idx < N) {
            off[idx] = run;
            run += c[k];
            dinv[idx] = rsqrtf((float)(c[k] + 1));  // deg includes self-loop
            cnt[idx] = 0;                           // reused as cursor in k_place
        }
    }
}

// ---------- K4: xws = dinv .* (x @ W)  (fp32, K-chunked LDS, 34KB/block) ----------
// Block 256 threads = 128 rows. K processed in 4 chunks of 32 so LDS stays small
// (W-chunk 16KB + x-chunk 18KB) -> occupancy VGPR-capped (~3 blocks/CU) instead
// of LDS-capped at 1. x-tile row stride padded to 9 float4: the 4 distinct row
// addresses of each xv read land on distinct bank quads.
__global__ __launch_bounds__(256) void k_gemm(const float* __restrict__ x,
                                              const float* __restrict__ W,
                                              const float* __restrict__ dinv,
                                              float* __restrict__ xws, int N) {
    __shared__ float4 ws4[KC * 32];   // [k][c4]        16 KB
    __shared__ float4 xt4[128 * 9];   // [r][k4] pad+1  18 KB
    int tid = threadIdx.x;
    int row0 = blockIdx.x * 128;
    int rg = tid >> 4;  // 0..15 row group (8 rows)
    int cg = tid & 15;  // 0..15 col group (4+4 cols)

    float acc[8][8];
#pragma unroll
    for (int i = 0; i < 8; ++i)
#pragma unroll
        for (int j = 0; j < 8; ++j) acc[i][j] = 0.f;

    for (int q = 0; q < 4; ++q) {
        // stage W chunk: k in [32q, 32q+32)
        for (int t = tid; t < KC * 32; t += 256) {
            int k = t >> 5, c4 = t & 31;
            ws4[t] = ((const float4*)W)[(q * KC + k) * 32 + c4];
        }
        // stage x chunk: 8 float4 per row
        for (int t = tid; t < 128 * 8; t += 256) {
            int r = t >> 3, c4 = t & 7;
            int grow = row0 + r;
            float4 v = make_float4(0.f, 0.f, 0.f, 0.f);
            if (grow < N) v = ((const float4*)x)[grow * 32 + q * 8 + c4];
            xt4[r * 9 + c4] = v;
        }
        __syncthreads();

#pragma unroll
        for (int k4 = 0; k4 < 8; ++k4) {
            float4 xv[8];
#pragma unroll
            for (int i = 0; i < 8; ++i)
                xv[i] = xt4[(rg * 8 + i) * 9 + k4];
#pragma unroll
            for (int kk = 0; kk < 4; ++kk) {
                int k = k4 * 4 + kk;
                float4 w0 = ws4[k * 32 + cg];
                float4 w1 = ws4[k * 32 + 16 + cg];
#pragma unroll
                for (int i = 0; i < 8; ++i) {
                    float xs = ((const float*)&xv[i])[kk];
                    acc[i][0] = fmaf(xs, w0.x, acc[i][0]);
                    acc[i][1] = fmaf(xs, w0.y, acc[i][1]);
                    acc[i][2] = fmaf(xs, w0.z, acc[i][2]);
                    acc[i][3] = fmaf(xs, w0.w, acc[i][3]);
                    acc[i][4] = fmaf(xs, w1.x, acc[i][4]);
                    acc[i][5] = fmaf(xs, w1.y, acc[i][5]);
                    acc[i][6] = fmaf(xs, w1.z, acc[i][6]);
                    acc[i][7] = fmaf(xs, w1.w, acc[i][7]);
                }
            }
        }
        __syncthreads();
    }

    // epilogue: scale row by dinv[row] (gather then only needs adds)
#pragma unroll
    for (int i = 0; i < 8; ++i) {
        int grow = row0 + rg * 8 + i;
        if (grow < N) {
            float d = dinv[grow];
            ((float4*)xws)[grow * 32 + cg] =
                make_float4(acc[i][0] * d, acc[i][1] * d, acc[i][2] * d, acc[i][3] * d);
            ((float4*)xws)[grow * 32 + 16 + cg] =
                make_float4(acc[i][4] * d, acc[i][5] * d, acc[i][6] * d, acc[i][7] * d);
        }
    }
}

// ---------- K5: counting-sort edges by target -> CSR source list ----------
__global__ void k_place(const int* __restrict__ row, const int* __restrict__ col,
                        const int* __restrict__ off, int* __restrict__ cur,
                        int* __restrict__ srcs, int E) {
    int e = blockIdx.x * 256 + threadIdx.x;
    if (e < E) {
        int c = col[e];
        int p = atomicAdd(&cur[c], 1);
        srcs[off[c] + p] = row[e];
    }
}

// ---------- K6: gather-aggregate + fused BN stats ----------
// agg[i] = dinv_i * (sum_{r->i} xws[r] + xws[i]) + b   (xws pre-scaled by dinv)
__global__ __launch_bounds__(256) void k_gather(const float* __restrict__ xws,
                                                const float* __restrict__ dinv,
                                                const int* __restrict__ off,
                                                const int* __restrict__ srcs,
                                                const float* __restrict__ b,
                                                float* __restrict__ out,
                                                float* __restrict__ bn, int N) {
    int tid = threadIdx.x;
    int lane = tid & 63;
    int w = (blockIdx.x * 256 + tid) >> 6;
    int nw = (gridDim.x * 256) >> 6;
    float2 bb = ((const float2*)b)[lane];
    float2 s = make_float2(0.f, 0.f), qq = make_float2(0.f, 0.f);
    for (int i = w; i < N; i += nw) {
        float di = dinv[i];
        float2 acc = ((const float2*)xws)[i * 64 + lane];  // self-loop (pre-scaled)
        int e0 = off[i], e1 = off[i + 1];
        for (int j = e0; j < e1; ++j) {
            int r = srcs[j];
            float2 v = ((const float2*)xws)[r * 64 + lane];
            acc.x += v.x;
            acc.y += v.y;
        }
        float2 o;
        o.x = fmaf(acc.x, di, bb.x);
        o.y = fmaf(acc.y, di, bb.y);
        ((float2*)out)[i * 64 + lane] = o;
        s.x += o.x;
        s.y += o.y;
        qq.x = fmaf(o.x, o.x, qq.x);
        qq.y = fmaf(o.y, o.y, qq.y);
    }
    // fused BN stats: block-level LDS reduce, one atomic set per block
    __shared__ float ssum[HIDDEN];
    __shared__ float ssq[HIDDEN];
    if (tid < HIDDEN) { ssum[tid] = 0.f; ssq[tid] = 0.f; }
    __syncthreads();
    atomicAdd(&ssum[2 * lane],     s.x);
    atomicAdd(&ssum[2 * lane + 1], s.y);
    atomicAdd(&ssq[2 * lane],      qq.x);
    atomicAdd(&ssq[2 * lane + 1],  qq.y);
    __syncthreads();
    if (tid < HIDDEN) {
        atomicAdd(&bn[tid],          ssum[tid]);
        atomicAdd(&bn[HIDDEN + tid], ssq[tid]);
    }
}

// ---------- K8: BN normalize (biased var) + gamma/beta + ReLU, in place ----------
__global__ __launch_bounds__(256) void k_apply(float* __restrict__ out,
                                               const float* __restrict__ bn,
                                               const float* __restrict__ gamma,
                                               const float* __restrict__ beta,
                                               int total4, float invN) {
    __shared__ float sc[HIDDEN], sh[HIDDEN];
    int tid = threadIdx.x;
    if (tid < HIDDEN) {
        float mean = bn[tid] * invN;
        float var = bn[HIDDEN + tid] * invN - mean * mean;
        float inv = rsqrtf(var + BN_EPS);
        float g = gamma[tid] * inv;
        sc[tid] = g;
        sh[tid] = beta[tid] - mean * g;
    }
    __syncthreads();
    int idx = blockIdx.x * 256 + tid;
    if (idx < total4) {
        float4 v = ((float4*)out)[idx];
        int c = (idx & 31) * 4;
        v.x = fmaxf(fmaf(v.x, sc[c],     sh[c]),     0.f);
        v.y = fmaxf(fmaf(v.y, sc[c + 1], sh[c + 1]), 0.f);
        v.z = fmaxf(fmaf(v.z, sc[c + 2], sh[c + 2]), 0.f);
        v.w = fmaxf(fmaf(v.w, sc[c + 3], sh[c + 3]), 0.f);
        ((float4*)out)[idx] = v;
    }
}

extern "C" void kernel_launch(void* const* d_in, const int* in_sizes, int n_in,
                              void* d_out, int out_size, void* d_ws, size_t ws_size,
                              hipStream_t stream) {
    const float* x     = (const float*)d_in[0];
    const int*   edges = (const int*)d_in[1];   // [2, E] int32 (JAX x64-off)
    const float* W     = (const float*)d_in[2];
    const float* b     = (const float*)d_in[3];
    const float* gamma = (const float*)d_in[4];
    const float* beta  = (const float*)d_in[5];
    float* out = (float*)d_out;

    int N = in_sizes[0] / HIDDEN;
    int E = in_sizes[1] / 2;
    const int* row = edges;      // sources
    const int* col = edges + E;  // targets

    int NB = (N + SCAN_CHUNK - 1) / SCAN_CHUNK;

    // workspace carve (~56 MB): xws | dinv | cnt | off | srcs | bn | partials
    char* p = (char*)d_ws;
    float* xws      = (float*)p; p += (size_t)N * HIDDEN * sizeof(float);
    float* dinv     = (float*)p; p += (size_t)N * sizeof(float);
    int*   cnt      = (int*)p;   p += (size_t)N * sizeof(int);
    int*   off      = (int*)p;   p += ((size_t)N + 4) * sizeof(int);
    int*   srcs     = (int*)p;   p += (size_t)E * sizeof(int);
    float* bn       = (float*)p; p += 256 * sizeof(float);
    int*   partials = (int*)p;   p += (size_t)NB * sizeof(int);

    dim3 blk(256);
    k_zero <<<dim3((N + 255) / 256), blk, 0, stream>>>(cnt, bn, N);
    k_count<<<dim3((E + 255) / 256), blk, 0, stream>>>(col, cnt, E);
    k_partial<<<dim3(NB), blk, 0, stream>>>(cnt, partials, N);
    k_scan_partials<<<dim3(1), dim3(1024), 0, stream>>>(partials, off, NB, N);
    k_finalize<<<dim3(NB), blk, 0, stream>>>(cnt, partials, off, dinv, N);
    k_gemm <<<dim3((N + 127) / 128), blk, 0, stream>>>(x, W, dinv, xws, N);
    k_place<<<dim3((E + 255) / 256), blk, 0, stream>>>(row, col, off, cnt, srcs, E);
    k_gather<<<dim3(2048), blk, 0, stream>>>(xws, dinv, off, srcs, b, out, bn, N);
    int total4 = N * (HIDDEN / 4);
    k_apply<<<dim3((total4 + 255) / 256), blk, 0, stream>>>(out, bn, gamma, beta, total4,
                                                            1.0f / (float)N);
}

// Round 4
// 363.957 us; speedup vs baseline: 1.8501x; 1.0794x over previous
//
#include <hip/hip_runtime.h>
#include <cstddef>

#define HIDDEN 128
#define BN_EPS 1e-5f
#define SCAN_CHUNK 1024  // cnt elements per scan block
#define KC 32            // GEMM k-chunk

// RNE float->bf16 (manual, exact for non-NaN)
__device__ inline unsigned bf16_rne(float f) {
    unsigned u = __float_as_uint(f);
    return (u + 0x7fff + ((u >> 16) & 1)) >> 16;
}
__device__ inline unsigned pack2_bf16(float a, float b) {
    return bf16_rne(a) | (bf16_rne(b) << 16);
}

// ---------- K1: zero degree counters + BN accumulators ----------
__global__ void k_zero(int* __restrict__ cnt, float* __restrict__ bn, int N) {
    int i = blockIdx.x * 256 + threadIdx.x;
    if (i < N) cnt[i] = 0;
    if (blockIdx.x == 0 && threadIdx.x < 256) bn[threadIdx.x] = 0.f;
}

// ---------- K2: in-degree histogram over target nodes ----------
__global__ void k_count(const int* __restrict__ col, int* __restrict__ cnt, int E) {
    int e = blockIdx.x * 256 + threadIdx.x;
    if (e < E) atomicAdd(&cnt[col[e]], 1);
}

// ---------- K3a: per-block partial sums of cnt (1024 elems / block) ----------
__global__ __launch_bounds__(256) void k_partial(const int* __restrict__ cnt,
                                                 int* __restrict__ partials, int N) {
    __shared__ int s[256];
    int tid = threadIdx.x;
    int base = blockIdx.x * SCAN_CHUNK;
    int acc = 0;
#pragma unroll
    for (int k = 0; k < 4; ++k) {
        int idx = base + tid * 4 + k;
        if (idx < N) acc += cnt[idx];
    }
    s[tid] = acc;
    __syncthreads();
    for (int o = 128; o > 0; o >>= 1) {
        if (tid < o) s[tid] += s[tid + o];
        __syncthreads();
    }
    if (tid == 0) partials[blockIdx.x] = s[0];
}

// ---------- K3b: single-block exclusive scan of partials (all in LDS) ----------
__global__ __launch_bounds__(1024) void k_scan_partials(int* __restrict__ partials,
                                                        int* __restrict__ off,
                                                        int NB, int N) {
    __shared__ int s[1024];
    int tid = threadIdx.x;
    int v = (tid < NB) ? partials[tid] : 0;
    s[tid] = v;
    __syncthreads();
    for (int o = 1; o < 1024; o <<= 1) {
        int t = (tid >= o) ? s[tid - o] : 0;
        __syncthreads();
        s[tid] += t;
        __syncthreads();
    }
    if (tid < NB) partials[tid] = s[tid] - v;
    if (tid == NB - 1) off[N] = s[tid];
}

// ---------- K3c: block-local scan + base -> off, dinv, cnt reset ----------
__global__ __launch_bounds__(256) void k_finalize(int* __restrict__ cnt,
                                                  const int* __restrict__ partials,
                                                  int* __restrict__ off,
                                                  float* __restrict__ dinv, int N) {
    __shared__ int s[256];
    int tid = threadIdx.x;
    int base = blockIdx.x * SCAN_CHUNK;
    int c[4];
    int t = 0;
#pragma unroll
    for (int k = 0; k < 4; ++k) {
        int idx = base + tid * 4 + k;
        c[k] = (idx < N) ? cnt[idx] : 0;
        t += c[k];
    }
    s[tid] = t;
    __syncthreads();
    for (int o = 1; o < 256; o <<= 1) {
        int v = (tid >= o) ? s[tid - o] : 0;
        __syncthreads();
        s[tid] += v;
        __syncthreads();
    }
    int run = partials[blockIdx.x] + s[tid] - t;
#pragma unroll
    for (int k = 0; k < 4; ++k) {
        int idx = base + tid * 4 + k;
        if (idx < N) {
            off[idx] = run;
            run += c[k];
            dinv[idx] = rsqrtf((float)(c[k] + 1));  // deg includes self-loop
            cnt[idx] = 0;                           // reused as cursor in k_place
        }
    }
}

// ---------- K4: xws(bf16) = dinv .* (x @ W)  (fp32 math, K-chunked LDS) ----------
// Block 256 threads = 128 rows; K in 4 chunks of 32 (LDS 34KB -> ~3 blocks/CU).
// Epilogue scales by dinv[row] and packs RNE bf16 (halves gather read bytes).
__global__ __launch_bounds__(256) void k_gemm(const float* __restrict__ x,
                                              const float* __restrict__ W,
                                              const float* __restrict__ dinv,
                                              unsigned* __restrict__ xu, int N) {
    __shared__ float4 ws4[KC * 32];   // 16 KB
    __shared__ float4 xt4[128 * 9];   // 18 KB (row stride 9: bank-quad spread)
    int tid = threadIdx.x;
    int row0 = blockIdx.x * 128;
    int rg = tid >> 4;  // 0..15 row group (8 rows)
    int cg = tid & 15;  // 0..15 col group (4+4 cols)

    float acc[8][8];
#pragma unroll
    for (int i = 0; i < 8; ++i)
#pragma unroll
        for (int j = 0; j < 8; ++j) acc[i][j] = 0.f;

    for (int q = 0; q < 4; ++q) {
        for (int t = tid; t < KC * 32; t += 256) {
            int k = t >> 5, c4 = t & 31;
            ws4[t] = ((const float4*)W)[(q * KC + k) * 32 + c4];
        }
        for (int t = tid; t < 128 * 8; t += 256) {
            int r = t >> 3, c4 = t & 7;
            int grow = row0 + r;
            float4 v = make_float4(0.f, 0.f, 0.f, 0.f);
            if (grow < N) v = ((const float4*)x)[grow * 32 + q * 8 + c4];
            xt4[r * 9 + c4] = v;
        }
        __syncthreads();

#pragma unroll
        for (int k4 = 0; k4 < 8; ++k4) {
            float4 xv[8];
#pragma unroll
            for (int i = 0; i < 8; ++i)
                xv[i] = xt4[(rg * 8 + i) * 9 + k4];
#pragma unroll
            for (int kk = 0; kk < 4; ++kk) {
                int k = k4 * 4 + kk;
                float4 w0 = ws4[k * 32 + cg];
                float4 w1 = ws4[k * 32 + 16 + cg];
#pragma unroll
                for (int i = 0; i < 8; ++i) {
                    float xs = ((const float*)&xv[i])[kk];
                    acc[i][0] = fmaf(xs, w0.x, acc[i][0]);
                    acc[i][1] = fmaf(xs, w0.y, acc[i][1]);
                    acc[i][2] = fmaf(xs, w0.z, acc[i][2]);
                    acc[i][3] = fmaf(xs, w0.w, acc[i][3]);
                    acc[i][4] = fmaf(xs, w1.x, acc[i][4]);
                    acc[i][5] = fmaf(xs, w1.y, acc[i][5]);
                    acc[i][6] = fmaf(xs, w1.z, acc[i][6]);
                    acc[i][7] = fmaf(xs, w1.w, acc[i][7]);
                }
            }
        }
        __syncthreads();
    }

    // epilogue: scale by dinv, pack to bf16 (row = 64 uints = 128 bf16)
#pragma unroll
    for (int i = 0; i < 8; ++i) {
        int grow = row0 + rg * 8 + i;
        if (grow < N) {
            float d = dinv[grow];
            uint2 p0, p1;
            p0.x = pack2_bf16(acc[i][0] * d, acc[i][1] * d);
            p0.y = pack2_bf16(acc[i][2] * d, acc[i][3] * d);
            p1.x = pack2_bf16(acc[i][4] * d, acc[i][5] * d);
            p1.y = pack2_bf16(acc[i][6] * d, acc[i][7] * d);
            ((uint2*)(xu + (size_t)grow * 64))[cg]      = p0;  // elems 4cg..4cg+3
            ((uint2*)(xu + (size_t)grow * 64))[16 + cg] = p1;  // elems 64+4cg..
        }
    }
}

// ---------- K5: counting-sort edges by target -> CSR source list ----------
__global__ void k_place(const int* __restrict__ row, const int* __restrict__ col,
                        const int* __restrict__ off, int* __restrict__ cur,
                        int* __restrict__ srcs, int E) {
    int e = blockIdx.x * 256 + threadIdx.x;
    if (e < E) {
        int c = col[e];
        int p = atomicAdd(&cur[c], 1);
        srcs[off[c] + p] = row[e];
    }
}

// ---------- K6: gather-aggregate (bf16 rows, unroll x4) + fused BN stats ----------
// agg[i] = dinv_i * (sum_{r->i} xws[r] + xws[i]) + b   (xws pre-scaled by dinv)
__global__ __launch_bounds__(256) void k_gather(const unsigned* __restrict__ xu,
                                                const float* __restrict__ dinv,
                                                const int* __restrict__ off,
                                                const int* __restrict__ srcs,
                                                const float* __restrict__ b,
                                                float* __restrict__ out,
                                                float* __restrict__ bn, int N) {
    int tid = threadIdx.x;
    int lane = tid & 63;
    int w = (blockIdx.x * 256 + tid) >> 6;
    int nw = (gridDim.x * 256) >> 6;
    float2 bb = ((const float2*)b)[lane];
    float2 s = make_float2(0.f, 0.f), qq = make_float2(0.f, 0.f);
    for (int i = w; i < N; i += nw) {
        float di = dinv[i];
        unsigned su = xu[(size_t)i * 64 + lane];  // self-loop (pre-scaled)
        float ax = __uint_as_float(su << 16);
        float ay = __uint_as_float(su & 0xffff0000u);
        int e0 = off[i], e1 = off[i + 1];
        int j = e0;
        for (; j + 4 <= e1; j += 4) {  // 4 rows in flight
            int r0 = srcs[j], r1 = srcs[j + 1], r2 = srcs[j + 2], r3 = srcs[j + 3];
            unsigned u0 = xu[(size_t)r0 * 64 + lane];
            unsigned u1 = xu[(size_t)r1 * 64 + lane];
            unsigned u2 = xu[(size_t)r2 * 64 + lane];
            unsigned u3 = xu[(size_t)r3 * 64 + lane];
            ax += __uint_as_float(u0 << 16) + __uint_as_float(u1 << 16)
                + __uint_as_float(u2 << 16) + __uint_as_float(u3 << 16);
            ay += __uint_as_float(u0 & 0xffff0000u) + __uint_as_float(u1 & 0xffff0000u)
                + __uint_as_float(u2 & 0xffff0000u) + __uint_as_float(u3 & 0xffff0000u);
        }
        for (; j < e1; ++j) {
            int r = srcs[j];
            unsigned u = xu[(size_t)r * 64 + lane];
            ax += __uint_as_float(u << 16);
            ay += __uint_as_float(u & 0xffff0000u);
        }
        float ox = fmaf(ax, di, bb.x);
        float oy = fmaf(ay, di, bb.y);
        ((float2*)out)[(size_t)i * 64 + lane] = make_float2(ox, oy);
        s.x += ox;
        s.y += oy;
        qq.x = fmaf(ox, ox, qq.x);
        qq.y = fmaf(oy, oy, qq.y);
    }
    // fused BN stats: block-level LDS reduce, one atomic set per block
    __shared__ float ssum[HIDDEN];
    __shared__ float ssq[HIDDEN];
    if (tid < HIDDEN) { ssum[tid] = 0.f; ssq[tid] = 0.f; }
    __syncthreads();
    atomicAdd(&ssum[2 * lane],     s.x);
    atomicAdd(&ssum[2 * lane + 1], s.y);
    atomicAdd(&ssq[2 * lane],      qq.x);
    atomicAdd(&ssq[2 * lane + 1],  qq.y);
    __syncthreads();
    if (tid < HIDDEN) {
        atomicAdd(&bn[tid],          ssum[tid]);
        atomicAdd(&bn[HIDDEN + tid], ssq[tid]);
    }
}

// ---------- K8: BN normalize (biased var) + gamma/beta + ReLU, in place ----------
__global__ __launch_bounds__(256) void k_apply(float* __restrict__ out,
                                               const float* __restrict__ bn,
                                               const float* __restrict__ gamma,
                                               const float* __restrict__ beta,
                                               int total4, float invN) {
    __shared__ float sc[HIDDEN], sh[HIDDEN];
    int tid = threadIdx.x;
    if (tid < HIDDEN) {
        float mean = bn[tid] * invN;
        float var = bn[HIDDEN + tid] * invN - mean * mean;
        float inv = rsqrtf(var + BN_EPS);
        float g = gamma[tid] * inv;
        sc[tid] = g;
        sh[tid] = beta[tid] - mean * g;
    }
    __syncthreads();
    int idx = blockIdx.x * 256 + tid;
    if (idx < total4) {
        float4 v = ((float4*)out)[idx];
        int c = (idx & 31) * 4;
        v.x = fmaxf(fmaf(v.x, sc[c],     sh[c]),     0.f);
        v.y = fmaxf(fmaf(v.y, sc[c + 1], sh[c + 1]), 0.f);
        v.z = fmaxf(fmaf(v.z, sc[c + 2], sh[c + 2]), 0.f);
        v.w = fmaxf(fmaf(v.w, sc[c + 3], sh[c + 3]), 0.f);
        ((float4*)out)[idx] = v;
    }
}

extern "C" void kernel_launch(void* const* d_in, const int* in_sizes, int n_in,
                              void* d_out, int out_size, void* d_ws, size_t ws_size,
                              hipStream_t stream) {
    const float* x     = (const float*)d_in[0];
    const int*   edges = (const int*)d_in[1];   // [2, E] int32 (JAX x64-off)
    const float* W     = (const float*)d_in[2];
    const float* b     = (const float*)d_in[3];
    const float* gamma = (const float*)d_in[4];
    const float* beta  = (const float*)d_in[5];
    float* out = (float*)d_out;

    int N = in_sizes[0] / HIDDEN;
    int E = in_sizes[1] / 2;
    const int* row = edges;      // sources
    const int* col = edges + E;  // targets

    int NB = (N + SCAN_CHUNK - 1) / SCAN_CHUNK;

    // workspace carve (~31 MB): xu(bf16) | dinv | cnt | off | srcs | bn | partials
    char* p = (char*)d_ws;
    unsigned* xu    = (unsigned*)p; p += (size_t)N * 64 * sizeof(unsigned);  // 128 bf16/row
    float* dinv     = (float*)p; p += (size_t)N * sizeof(float);
    int*   cnt      = (int*)p;   p += (size_t)N * sizeof(int);
    int*   off      = (int*)p;   p += ((size_t)N + 4) * sizeof(int);
    int*   srcs     = (int*)p;   p += (size_t)E * sizeof(int);
    float* bn       = (float*)p; p += 256 * sizeof(float);
    int*   partials = (int*)p;   p += (size_t)NB * sizeof(int);

    dim3 blk(256);
    k_zero <<<dim3((N + 255) / 256), blk, 0, stream>>>(cnt, bn, N);
    k_count<<<dim3((E + 255) / 256), blk, 0, stream>>>(col, cnt, E);
    k_partial<<<dim3(NB), blk, 0, stream>>>(cnt, partials, N);
    k_scan_partials<<<dim3(1), dim3(1024), 0, stream>>>(partials, off, NB, N);
    k_finalize<<<dim3(NB), blk, 0, stream>>>(cnt, partials, off, dinv, N);
    k_gemm <<<dim3((N + 127) / 128), blk, 0, stream>>>(x, W, dinv, xu, N);
    k_place<<<dim3((E + 255) / 256), blk, 0, stream>>>(row, col, off, cnt, srcs, E);
    k_gather<<<dim3(2048), blk, 0, stream>>>(xu, dinv, off, srcs, b, out, bn, N);
    int total4 = N * (HIDDEN / 4);
    k_apply<<<dim3((total4 + 255) / 256), blk, 0, stream>>>(out, bn, gamma, beta, total4,
                                                            1.0f / (float)N);
}